// Round 5
// baseline (475.074 us; speedup 1.0000x reference)
//
#include <hip/hip_runtime.h>

typedef _Float16 f16;
typedef _Float16 f16x4 __attribute__((ext_vector_type(4)));
typedef _Float16 f16x8 __attribute__((ext_vector_type(8)));
typedef float f32x4 __attribute__((ext_vector_type(4)));

#define MFMA32(A, B, C) __builtin_amdgcn_mfma_f32_16x16x32_f16((A), (B), (C), 0, 0, 0)
#if __has_builtin(__builtin_amdgcn_mfma_f32_16x16x16_f16)
#define MFMA16(A, B, C) __builtin_amdgcn_mfma_f32_16x16x16_f16((A), (B), (C), 0, 0, 0)
#else
#define MFMA16(A, B, C) __builtin_amdgcn_mfma_f32_16x16x16f16((A), (B), (C), 0, 0, 0)
#endif

// ---------------- prep: deinterleave weights to f16, bias tables ----------------
__global__ void prep_kernel(const float* __restrict__ Wq, const float* __restrict__ bqkv,
                            const float* __restrict__ Wo, const float* __restrict__ Brel,
                            f16* __restrict__ wqd, f16* __restrict__ wod,
                            float* __restrict__ bqd, f16* __restrict__ biasreg) {
  int tid = blockIdx.x * blockDim.x + threadIdx.x;
  int nthr = gridDim.x * blockDim.x;
  for (int i = tid; i < 3 * 192 * 192; i += nthr) {
    int c = i % 192, n = (i / 192) % 192, kk = i / (192 * 192);
    wqd[i] = (f16)Wq[(size_t)(n * 3 + kk) * 192 + c];
  }
  for (int i = tid; i < 192 * 192; i += nthr) wod[i] = (f16)Wo[i];
  for (int i = tid; i < 3 * 192; i += nthr) {
    int n = i % 192, kk = i / 192;
    bqd[i] = bqkv[n * 3 + kk];
  }
  for (int idx = tid; idx < 4 * 4 * 4 * 64 * 4; idx += nthr) {
    int m = idx & 3, lane = (idx >> 2) & 63, jt = (idx >> 8) & 3,
        itt = (idx >> 10) & 3, t = idx >> 12;
    int i = itt * 16 + (lane & 15);
    int j = jt * 16 + 4 * (lane >> 4) + m;
    float v = -60000.0f;
    if (i < 49 && j < 49) {
      bool msk = false;
      if (t & 2) msk |= ((i / 7 >= 4) != (j / 7 >= 4));
      if (t & 1) msk |= ((i % 7 >= 4) != (j % 7 >= 4));
      if (!msk) {
        // numpy PyArray_Arange + DOUBLE_fill: delta = fl(1+1/7) - 1
        volatile double one = 1.0;
        volatile double step = 1.0 / 7.0;
        volatile double b1 = one + step;
        volatile double delta = b1 - one;
        volatile double mj = (double)j * delta;
        volatile double sj = 1.0 + mj;
        volatile double mi = (double)i * delta;
        volatile double si = 1.0 + mi;
        double d = (double)sj - (double)si;
        int xd = (int)d;
        int yd = (j % 7) - (i % 7);
        int xm = ((xd % 13) + 13) % 13;
        int ym = ((yd % 13) + 13) % 13;
        v = Brel[xm * 13 + ym];
      }
    }
    biasreg[idx] = (f16)v;
  }
}

// ---------------- fused shifted-window MSA: one block per (batch-pair, window) ----------------
// Two windows (same wh,ww; batches 2p, 2p+1) per block: every weight/bias fragment
// load feeds 2x the MFMAs. All intermediates in registers via K=16 MFMA C-chaining.
__launch_bounds__(384, 3)
__global__ void swin_kernel(const float* __restrict__ x,
                            const float* __restrict__ bqd,
                            const float* __restrict__ bout,
                            const f16* __restrict__ wqd,
                            const f16* __restrict__ wod,
                            const f16* __restrict__ biasreg,
                            float* __restrict__ out) {
  __shared__ __align__(16) unsigned char xsm[2 * 64 * 384];  // per tile: [row][192 f16] swizzled

  const int tid = threadIdx.x;
  const int bid = blockIdx.x;
  const int p  = bid >> 6;            // batch pair: b = 2p+t
  const int wh = (bid >> 3) & 7;
  const int ww = bid & 7;
  const int lane = tid & 63;
  const int wv = tid >> 6;            // wave == head
  const int lr = lane & 15;
  const int lg = lane >> 4;

#define XP(t, row, cb) ((void*)(xsm + (t) * 24576 + (row) * 384 + ((cb) ^ (((row) & 7) << 4))))

  // ---- phase 0: stage both x windows (roll -4) into swizzled LDS, f16 ----
  #pragma unroll
  for (int t = 0; t < 2; ++t) {
    const float* xb = x + (size_t)(2 * p + t) * (3136 * 192);
    for (int idx = tid; idx < 49 * 48; idx += 384) {
      int tok = idx / 48, c4 = idx % 48;
      int m1 = tok / 7, m2 = tok % 7;
      int y  = wh * 7 + m1 + 4; if (y  >= 56) y  -= 56;
      int xx = ww * 7 + m2 + 4; if (xx >= 56) xx -= 56;
      float4 v = *(const float4*)(xb + ((y * 56 + xx) * 192 + c4 * 4));
      f16x4 h = { (f16)v.x, (f16)v.y, (f16)v.z, (f16)v.w };
      *(f16x4*)XP(t, tok, c4 * 8) = h;
    }
    for (int idx = tid; idx < 15 * 24; idx += 384) {   // zero rows 49..63
      int tok = 49 + idx / 24, c8 = idx % 24;
      f16x8 z = {};
      *(f16x8*)XP(t, tok, c8 * 16) = z;
    }
  }
  __syncthreads();   // B1

  // ---- phase 1a: Qt,Kt = W @ x^T for both tiles (C[n][i]) ----
  f16x4 qtf[2][2][4], ktf[2][2][4];    // [tile][nt][it]
  #pragma unroll
  for (int nt = 0; nt < 2; ++nt) {
    f32x4 qacc[2][4], kacc[2][4];
    #pragma unroll
    for (int t = 0; t < 2; ++t)
      #pragma unroll
      for (int it = 0; it < 4; ++it) {
        qacc[t][it] = (f32x4){0.f, 0.f, 0.f, 0.f};
        kacc[t][it] = (f32x4){0.f, 0.f, 0.f, 0.f};
      }
    #pragma unroll
    for (int ks = 0; ks < 6; ++ks) {
      const size_t roff = (size_t)(wv * 32 + nt * 16 + lr) * 192 + ks * 32 + lg * 8;
      f16x8 wqf = *(const f16x8*)(wqd + roff);
      f16x8 wkf = *(const f16x8*)(wqd + 192 * 192 + roff);
      #pragma unroll
      for (int t = 0; t < 2; ++t) {
        f16x8 a[4];
        #pragma unroll
        for (int it = 0; it < 4; ++it)
          a[it] = *(const f16x8*)XP(t, it * 16 + lr, ks * 64 + lg * 16);
        #pragma unroll
        for (int it = 0; it < 4; ++it) {
          qacc[t][it] = MFMA32(wqf, a[it], qacc[t][it]);
          kacc[t][it] = MFMA32(wkf, a[it], kacc[t][it]);
        }
      }
    }
    const float SCALE = 0.17677669529663687f;  // 1/sqrt(32) folded into Q
    float4 bq4 = *(const float4*)(bqd + wv * 32 + nt * 16 + 4 * lg);
    float4 bk4 = *(const float4*)(bqd + 192 + wv * 32 + nt * 16 + 4 * lg);
    #pragma unroll
    for (int t = 0; t < 2; ++t)
      #pragma unroll
      for (int it = 0; it < 4; ++it) {
        f16x4 q, k;
        q[0] = (f16)((qacc[t][it][0] + bq4.x) * SCALE);
        q[1] = (f16)((qacc[t][it][1] + bq4.y) * SCALE);
        q[2] = (f16)((qacc[t][it][2] + bq4.z) * SCALE);
        q[3] = (f16)((qacc[t][it][3] + bq4.w) * SCALE);
        k[0] = (f16)(kacc[t][it][0] + bk4.x);
        k[1] = (f16)(kacc[t][it][1] + bk4.y);
        k[2] = (f16)(kacc[t][it][2] + bk4.z);
        k[3] = (f16)(kacc[t][it][3] + bk4.w);
        qtf[t][nt][it] = q; ktf[t][nt][it] = k;
      }
  }

  // ---- bias table (register layout; shared by both tiles — same wh,ww) ----
  f16x4 br[4][4];
  {
    int msk = ((wh == 7) ? 2 : 0) | ((ww == 7) ? 1 : 0);
    #pragma unroll
    for (int itt = 0; itt < 4; ++itt)
      #pragma unroll
      for (int jt = 0; jt < 4; ++jt)
        br[itt][jt] = *(const f16x4*)(biasreg + ((((msk * 4 + itt) * 4 + jt) * 64 + lane) * 4));
  }

  // ---- per tile: S^T -> softmax -> V -> O -> LDS ----
  #pragma unroll
  for (int t = 0; t < 2; ++t) {
    // S^T = K @ Q^T
    f32x4 sacc[4][4];
    #pragma unroll
    for (int jt = 0; jt < 4; ++jt)
      #pragma unroll
      for (int it = 0; it < 4; ++it) {
        f32x4 c = (f32x4){0.f, 0.f, 0.f, 0.f};
        c = MFMA16(ktf[t][0][jt], qtf[t][0][it], c);
        sacc[jt][it] = MFMA16(ktf[t][1][jt], qtf[t][1][it], c);
      }
    // softmax per query-col (rows j lane-local)
    f16x4 paf[4][4];   // [jt][it] normalized P
    #pragma unroll
    for (int itt = 0; itt < 4; ++itt) {
      float sv[16];
      #pragma unroll
      for (int jt = 0; jt < 4; ++jt)
        #pragma unroll
        for (int m = 0; m < 4; ++m)
          sv[jt * 4 + m] = sacc[jt][itt][m] + (float)br[itt][jt][m];
      float mx = sv[0];
      #pragma unroll
      for (int q = 1; q < 16; ++q) mx = fmaxf(mx, sv[q]);
      mx = fmaxf(mx, __shfl_xor(mx, 16));
      mx = fmaxf(mx, __shfl_xor(mx, 32));
      float sum = 0.f;
      #pragma unroll
      for (int q = 0; q < 16; ++q) { sv[q] = __expf(sv[q] - mx); sum += sv[q]; }
      sum += __shfl_xor(sum, 16);
      sum += __shfl_xor(sum, 32);
      float rv = 1.0f / sum;
      #pragma unroll
      for (int jt = 0; jt < 4; ++jt) {
        f16x4 pk = { (f16)(sv[jt*4+0] * rv), (f16)(sv[jt*4+1] * rv),
                     (f16)(sv[jt*4+2] * rv), (f16)(sv[jt*4+3] * rv) };
        paf[jt][itt] = pk;
      }
    }
    // V = x @ Wv^T (this tile)
    f16x4 vf[4][2];
    {
      f32x4 vacc[4][2];
      #pragma unroll
      for (int jt = 0; jt < 4; ++jt)
        #pragma unroll
        for (int et = 0; et < 2; ++et)
          vacc[jt][et] = (f32x4){0.f, 0.f, 0.f, 0.f};
      #pragma unroll
      for (int ks = 0; ks < 6; ++ks) {
        f16x8 a[4];
        #pragma unroll
        for (int jt = 0; jt < 4; ++jt)
          a[jt] = *(const f16x8*)XP(t, jt * 16 + lr, ks * 64 + lg * 16);
        #pragma unroll
        for (int et = 0; et < 2; ++et) {
          f16x8 wvf = *(const f16x8*)(wqd + 2 * 192 * 192 +
                        (size_t)(wv * 32 + et * 16 + lr) * 192 + ks * 32 + lg * 8);
          #pragma unroll
          for (int jt = 0; jt < 4; ++jt)
            vacc[jt][et] = MFMA32(a[jt], wvf, vacc[jt][et]);
        }
      }
      #pragma unroll
      for (int et = 0; et < 2; ++et) {
        float bv = bqd[2 * 192 + wv * 32 + et * 16 + lr];
        #pragma unroll
        for (int jt = 0; jt < 4; ++jt) {
          f16x4 v;
          #pragma unroll
          for (int m = 0; m < 4; ++m) v[m] = (f16)(vacc[jt][et][m] + bv);
          vf[jt][et] = v;
        }
      }
    }
    // O = P @ V
    f32x4 oacc[4][2];
    #pragma unroll
    for (int it = 0; it < 4; ++it)
      #pragma unroll
      for (int et = 0; et < 2; ++et) {
        f32x4 c = (f32x4){0.f, 0.f, 0.f, 0.f};
        #pragma unroll
        for (int jt = 0; jt < 4; ++jt)
          c = MFMA16(paf[jt][it], vf[jt][et], c);
        oacc[it][et] = c;
      }
    __syncthreads();   // all waves finished reading xsm[t] (phase 1b) -> safe to overwrite
    #pragma unroll
    for (int it = 0; it < 4; ++it)
      #pragma unroll
      for (int et = 0; et < 2; ++et)
        #pragma unroll
        for (int m = 0; m < 4; ++m) {
          int i = it * 16 + 4 * lg + m;
          *(f16*)XP(t, i, wv * 64 + et * 32 + lr * 2) = (f16)(oacc[it][et][m]);
        }
  }
  __syncthreads();   // B3: O complete for both tiles

  // ---- phase 3: Z = O @ Wo^T + bo, rolled (+3) scatter, both tiles ----
  #pragma unroll
  for (int nt = 0; nt < 2; ++nt) {
    f32x4 zacc[2][4];
    #pragma unroll
    for (int t = 0; t < 2; ++t)
      #pragma unroll
      for (int it = 0; it < 4; ++it)
        zacc[t][it] = (f32x4){0.f, 0.f, 0.f, 0.f};
    #pragma unroll
    for (int ks = 0; ks < 6; ++ks) {
      f16x8 bw = *(const f16x8*)(wod + (size_t)(wv * 32 + nt * 16 + lr) * 192 + ks * 32 + lg * 8);
      #pragma unroll
      for (int t = 0; t < 2; ++t) {
        f16x8 a[4];
        #pragma unroll
        for (int it = 0; it < 4; ++it)
          a[it] = *(const f16x8*)XP(t, it * 16 + lr, ks * 64 + lg * 16);
        #pragma unroll
        for (int it = 0; it < 4; ++it)
          zacc[t][it] = MFMA32(a[it], bw, zacc[t][it]);
      }
    }
    int n = wv * 32 + nt * 16 + lr;
    float bo = bout[n];
    #pragma unroll
    for (int t = 0; t < 2; ++t) {
      float* outb = out + (size_t)(2 * p + t) * (3136 * 192);
      #pragma unroll
      for (int it = 0; it < 4; ++it) {
        #pragma unroll
        for (int r = 0; r < 4; ++r) {
          int i = it * 16 + lg * 4 + r;
          if (i < 49) {
            int m1 = i / 7, m2 = i % 7;
            int y  = wh * 7 + m1 + 3; if (y  >= 56) y  -= 56;
            int xx = ww * 7 + m2 + 3; if (xx >= 56) xx -= 56;
            outb[(size_t)(y * 56 + xx) * 192 + n] = zacc[t][it][r] + bo;
          }
        }
      }
    }
  }
#undef XP
}

extern "C" void kernel_launch(void* const* d_in, const int* in_sizes, int n_in,
                              void* d_out, int out_size, void* d_ws, size_t ws_size,
                              hipStream_t stream) {
  const float* x    = (const float*)d_in[0];
  const float* Wq   = (const float*)d_in[1];
  const float* bq   = (const float*)d_in[2];
  const float* Wo   = (const float*)d_in[3];
  const float* bo   = (const float*)d_in[4];
  const float* Brel = (const float*)d_in[5];

  f16*   wqd     = (f16*)d_ws;                         // 3*192*192*2 = 221184 B
  f16*   wod     = (f16*)((char*)d_ws + 0x38000);      // 192*192*2   =  73728 B
  float* bqd     = (float*)((char*)d_ws + 0x4A000);    // 3*192*4     =   2304 B
  f16*   biasreg = (f16*)((char*)d_ws + 0x4B000);      // 4*4*4*64*4*2=  32768 B

  hipLaunchKernelGGL(prep_kernel, dim3(256), dim3(256), 0, stream,
                     Wq, bq, Wo, Brel, wqd, wod, bqd, biasreg);
  hipLaunchKernelGGL(swin_kernel, dim3(16 * 8 * 8), dim3(384), 0, stream,
                     x, bqd, bo, wqd, wod, biasreg, (float*)d_out);
}

// Round 6
// 215.193 us; speedup vs baseline: 2.2077x; 2.2077x over previous
//
#include <hip/hip_runtime.h>

typedef _Float16 f16;
typedef _Float16 f16x4 __attribute__((ext_vector_type(4)));
typedef _Float16 f16x8 __attribute__((ext_vector_type(8)));
typedef float f32x4 __attribute__((ext_vector_type(4)));

#define MFMA32(A, B, C) __builtin_amdgcn_mfma_f32_16x16x32_f16((A), (B), (C), 0, 0, 0)
#if __has_builtin(__builtin_amdgcn_mfma_f32_16x16x16_f16)
#define MFMA16(A, B, C) __builtin_amdgcn_mfma_f32_16x16x16_f16((A), (B), (C), 0, 0, 0)
#else
#define MFMA16(A, B, C) __builtin_amdgcn_mfma_f32_16x16x16f16((A), (B), (C), 0, 0, 0)
#endif

// ---------------- prep: deinterleave weights to f16, bias tables ----------------
__global__ void prep_kernel(const float* __restrict__ Wq, const float* __restrict__ bqkv,
                            const float* __restrict__ Wo, const float* __restrict__ Brel,
                            f16* __restrict__ wqd, f16* __restrict__ wod,
                            float* __restrict__ bqd, f16* __restrict__ biasreg) {
  int tid = blockIdx.x * blockDim.x + threadIdx.x;
  int nthr = gridDim.x * blockDim.x;
  for (int i = tid; i < 3 * 192 * 192; i += nthr) {
    int c = i % 192, n = (i / 192) % 192, kk = i / (192 * 192);
    wqd[i] = (f16)Wq[(size_t)(n * 3 + kk) * 192 + c];
  }
  for (int i = tid; i < 192 * 192; i += nthr) wod[i] = (f16)Wo[i];
  for (int i = tid; i < 3 * 192; i += nthr) {
    int n = i % 192, kk = i / 192;
    bqd[i] = bqkv[n * 3 + kk];
  }
  for (int idx = tid; idx < 4 * 4 * 4 * 64 * 4; idx += nthr) {
    int m = idx & 3, lane = (idx >> 2) & 63, jt = (idx >> 8) & 3,
        itt = (idx >> 10) & 3, t = idx >> 12;
    int i = itt * 16 + (lane & 15);
    int j = jt * 16 + 4 * (lane >> 4) + m;
    float v = -60000.0f;
    if (i < 49 && j < 49) {
      bool msk = false;
      if (t & 2) msk |= ((i / 7 >= 4) != (j / 7 >= 4));
      if (t & 1) msk |= ((i % 7 >= 4) != (j % 7 >= 4));
      if (!msk) {
        // numpy PyArray_Arange + DOUBLE_fill: delta = fl(1+1/7) - 1
        volatile double one = 1.0;
        volatile double step = 1.0 / 7.0;
        volatile double b1 = one + step;
        volatile double delta = b1 - one;
        volatile double mj = (double)j * delta;
        volatile double sj = 1.0 + mj;
        volatile double mi = (double)i * delta;
        volatile double si = 1.0 + mi;
        double d = (double)sj - (double)si;
        int xd = (int)d;
        int yd = (j % 7) - (i % 7);
        int xm = ((xd % 13) + 13) % 13;
        int ym = ((yd % 13) + 13) % 13;
        v = Brel[xm * 13 + ym];
      }
    }
    biasreg[idx] = (f16)v;
  }
}

// ---------------- fused shifted-window MSA: one block per (batch, window) ----------------
// All intermediates in registers via K=16 MFMA C-chaining; 24 KB swizzled LDS tile
// reused x -> O -> Z; epilogue writes full 128B lines cooperatively (no RFO).
__launch_bounds__(384, 3)
__global__ void swin_kernel(const float* __restrict__ x,
                            const float* __restrict__ bqd,
                            const float* __restrict__ bout,
                            const f16* __restrict__ wqd,
                            const f16* __restrict__ wod,
                            const f16* __restrict__ biasreg,
                            float* __restrict__ out) {
  __shared__ __align__(16) unsigned char xsm[64 * 384];  // [row][192 f16], swizzled

  const int tid = threadIdx.x;
  const int bid = blockIdx.x;
  const int b  = bid >> 6;
  const int wh = (bid >> 3) & 7;
  const int ww = bid & 7;
  const int lane = tid & 63;
  const int wv = tid >> 6;            // wave == head
  const int lr = lane & 15;
  const int lg = lane >> 4;

#define XP(row, cb) ((void*)(xsm + (row) * 384 + ((cb) ^ (((row) & 7) << 4))))

  // ---- phase 0: stage x window (roll -4) into swizzled LDS, f16 ----
  {
    const float* xb = x + (size_t)b * (3136 * 192);
    for (int idx = tid; idx < 49 * 48; idx += 384) {
      int t = idx / 48, c4 = idx % 48;
      int m1 = t / 7, m2 = t % 7;
      int y  = wh * 7 + m1 + 4; if (y  >= 56) y  -= 56;
      int xx = ww * 7 + m2 + 4; if (xx >= 56) xx -= 56;
      float4 v = *(const float4*)(xb + ((y * 56 + xx) * 192 + c4 * 4));
      f16x4 h = { (f16)v.x, (f16)v.y, (f16)v.z, (f16)v.w };
      *(f16x4*)XP(t, c4 * 8) = h;
    }
    for (int idx = tid; idx < 15 * 24; idx += 384) {   // zero rows 49..63
      int t = 49 + idx / 24, c8 = idx % 24;
      f16x8 z = {};
      *(f16x8*)XP(t, c8 * 16) = z;
    }
  }
  __syncthreads();   // B1

  // ---- bias table (register layout, coalesced, L2-resident) ----
  f16x4 br[4][4];
  {
    int msk = ((wh == 7) ? 2 : 0) | ((ww == 7) ? 1 : 0);
    #pragma unroll
    for (int itt = 0; itt < 4; ++itt)
      #pragma unroll
      for (int jt = 0; jt < 4; ++jt)
        br[itt][jt] = *(const f16x4*)(biasreg + ((((msk * 4 + itt) * 4 + jt) * 64 + lane) * 4));
  }

  // ---- phase 1a: Qt,Kt = W @ x^T  (C[n][i]: col i=lr, rows e=nt*16+4lg+m) ----
  f16x4 qtf[2][4], ktf[2][4];
  {
    f32x4 qacc[2][4], kacc[2][4];
    #pragma unroll
    for (int nt = 0; nt < 2; ++nt)
      #pragma unroll
      for (int it = 0; it < 4; ++it) {
        qacc[nt][it] = (f32x4){0.f, 0.f, 0.f, 0.f};
        kacc[nt][it] = (f32x4){0.f, 0.f, 0.f, 0.f};
      }
    #pragma unroll
    for (int ks = 0; ks < 6; ++ks) {
      f16x8 a[4];
      #pragma unroll
      for (int it = 0; it < 4; ++it)
        a[it] = *(const f16x8*)XP(it * 16 + lr, ks * 64 + lg * 16);
      #pragma unroll
      for (int nt = 0; nt < 2; ++nt) {
        const size_t roff = (size_t)(wv * 32 + nt * 16 + lr) * 192 + ks * 32 + lg * 8;
        f16x8 wqf = *(const f16x8*)(wqd + roff);                 // kk=0 plane
        f16x8 wkf = *(const f16x8*)(wqd + 192 * 192 + roff);     // kk=1 plane
        #pragma unroll
        for (int it = 0; it < 4; ++it) {
          qacc[nt][it] = MFMA32(wqf, a[it], qacc[nt][it]);
          kacc[nt][it] = MFMA32(wkf, a[it], kacc[nt][it]);
        }
      }
    }
    const float SCALE = 0.17677669529663687f;  // 1/sqrt(32) folded into Q
    #pragma unroll
    for (int nt = 0; nt < 2; ++nt) {
      float4 bq4 = *(const float4*)(bqd + wv * 32 + nt * 16 + 4 * lg);
      float4 bk4 = *(const float4*)(bqd + 192 + wv * 32 + nt * 16 + 4 * lg);
      #pragma unroll
      for (int it = 0; it < 4; ++it) {
        f16x4 q, k;
        q[0] = (f16)((qacc[nt][it][0] + bq4.x) * SCALE);
        q[1] = (f16)((qacc[nt][it][1] + bq4.y) * SCALE);
        q[2] = (f16)((qacc[nt][it][2] + bq4.z) * SCALE);
        q[3] = (f16)((qacc[nt][it][3] + bq4.w) * SCALE);
        k[0] = (f16)(kacc[nt][it][0] + bk4.x);
        k[1] = (f16)(kacc[nt][it][1] + bk4.y);
        k[2] = (f16)(kacc[nt][it][2] + bk4.z);
        k[3] = (f16)(kacc[nt][it][3] + bk4.w);
        qtf[nt][it] = q; ktf[nt][it] = k;
      }
    }
  }

  // ---- phase 2a: S^T = K @ Q^T ----
  f32x4 sacc[4][4];
  #pragma unroll
  for (int jt = 0; jt < 4; ++jt)
    #pragma unroll
    for (int it = 0; it < 4; ++it) {
      f32x4 c = (f32x4){0.f, 0.f, 0.f, 0.f};
      c = MFMA16(ktf[0][jt], qtf[0][it], c);
      sacc[jt][it] = MFMA16(ktf[1][jt], qtf[1][it], c);
    }

  // ---- softmax per query-col (rows j lane-local) ----
  f16x4 paf[4][4];   // [jt][it] normalized P as A-frags
  #pragma unroll
  for (int itt = 0; itt < 4; ++itt) {
    float sv[16];
    #pragma unroll
    for (int jt = 0; jt < 4; ++jt)
      #pragma unroll
      for (int m = 0; m < 4; ++m)
        sv[jt * 4 + m] = sacc[jt][itt][m] + (float)br[itt][jt][m];
    float mx = sv[0];
    #pragma unroll
    for (int t = 1; t < 16; ++t) mx = fmaxf(mx, sv[t]);
    mx = fmaxf(mx, __shfl_xor(mx, 16));
    mx = fmaxf(mx, __shfl_xor(mx, 32));
    float sum = 0.f;
    #pragma unroll
    for (int t = 0; t < 16; ++t) { sv[t] = __expf(sv[t] - mx); sum += sv[t]; }
    sum += __shfl_xor(sum, 16);
    sum += __shfl_xor(sum, 32);
    float rv = 1.0f / sum;
    #pragma unroll
    for (int jt = 0; jt < 4; ++jt) {
      f16x4 p = { (f16)(sv[jt*4+0] * rv), (f16)(sv[jt*4+1] * rv),
                  (f16)(sv[jt*4+2] * rv), (f16)(sv[jt*4+3] * rv) };
      paf[jt][itt] = p;
    }
  }

  // ---- phase 1b: V = x @ Wv^T  (C[j][e]) ----
  f16x4 vf[4][2];
  {
    f32x4 vacc[4][2];
    #pragma unroll
    for (int jt = 0; jt < 4; ++jt)
      #pragma unroll
      for (int et = 0; et < 2; ++et)
        vacc[jt][et] = (f32x4){0.f, 0.f, 0.f, 0.f};
    #pragma unroll
    for (int ks = 0; ks < 6; ++ks) {
      f16x8 a[4];
      #pragma unroll
      for (int jt = 0; jt < 4; ++jt)
        a[jt] = *(const f16x8*)XP(jt * 16 + lr, ks * 64 + lg * 16);
      #pragma unroll
      for (int et = 0; et < 2; ++et) {
        f16x8 wvf = *(const f16x8*)(wqd + 2 * 192 * 192 +
                      (size_t)(wv * 32 + et * 16 + lr) * 192 + ks * 32 + lg * 8);
        #pragma unroll
        for (int jt = 0; jt < 4; ++jt)
          vacc[jt][et] = MFMA32(a[jt], wvf, vacc[jt][et]);
      }
    }
    #pragma unroll
    for (int et = 0; et < 2; ++et) {
      float bv = bqd[2 * 192 + wv * 32 + et * 16 + lr];
      #pragma unroll
      for (int jt = 0; jt < 4; ++jt) {
        f16x4 v;
        #pragma unroll
        for (int m = 0; m < 4; ++m) v[m] = (f16)(vacc[jt][et][m] + bv);
        vf[jt][et] = v;
      }
    }
  }

  // ---- phase 2b: O = P @ V ----
  f32x4 oacc[4][2];
  #pragma unroll
  for (int it = 0; it < 4; ++it)
    #pragma unroll
    for (int et = 0; et < 2; ++et) {
      f32x4 c = (f32x4){0.f, 0.f, 0.f, 0.f};
      #pragma unroll
      for (int jt = 0; jt < 4; ++jt)
        c = MFMA16(paf[jt][it], vf[jt][et], c);
      oacc[it][et] = c;
    }

  __syncthreads();   // B2: all xs reads (phase 1a/1b) done everywhere

  // ---- O -> LDS (reuse xs region): O[i][head*32+e], swizzled ----
  #pragma unroll
  for (int it = 0; it < 4; ++it)
    #pragma unroll
    for (int et = 0; et < 2; ++et)
      #pragma unroll
      for (int m = 0; m < 4; ++m) {
        int i = it * 16 + 4 * lg + m;
        *(f16*)XP(i, wv * 64 + et * 32 + lr * 2) = (f16)(oacc[it][et][m]);
      }
  __syncthreads();   // B3

  // ---- phase 3: Z = O @ Wo^T + bo ----
  f32x4 zacc[2][4];
  {
    #pragma unroll
    for (int nt = 0; nt < 2; ++nt)
      #pragma unroll
      for (int it = 0; it < 4; ++it)
        zacc[nt][it] = (f32x4){0.f, 0.f, 0.f, 0.f};
    #pragma unroll
    for (int ks = 0; ks < 6; ++ks) {
      f16x8 a[4];
      #pragma unroll
      for (int it = 0; it < 4; ++it)
        a[it] = *(const f16x8*)XP(it * 16 + lr, ks * 64 + lg * 16);
      #pragma unroll
      for (int nt = 0; nt < 2; ++nt) {
        f16x8 bw = *(const f16x8*)(wod + (size_t)(wv * 32 + nt * 16 + lr) * 192 + ks * 32 + lg * 8);
        #pragma unroll
        for (int it = 0; it < 4; ++it)
          zacc[nt][it] = MFMA32(a[it], bw, zacc[nt][it]);
      }
    }
  }
  __syncthreads();   // B4: all xs reads (phase 3) done -> reuse xs for Z

  // ---- Z (+bias, f16) -> LDS ----
  #pragma unroll
  for (int nt = 0; nt < 2; ++nt) {
    int n = wv * 32 + nt * 16 + lr;
    float bo = bout[n];
    #pragma unroll
    for (int it = 0; it < 4; ++it)
      #pragma unroll
      for (int m = 0; m < 4; ++m) {
        int i = it * 16 + 4 * lg + m;
        *(f16*)XP(i, n * 2) = (f16)(zacc[nt][it][m] + bo);
      }
  }
  __syncthreads();   // B5

  // ---- cooperative fully-coalesced out write (full 128B lines, once) ----
  {
    float* outb = out + (size_t)b * (3136 * 192);
    for (int idx = tid; idx < 49 * 48; idx += 384) {
      int t = idx / 48, c4 = idx % 48;
      f16x4 z = *(const f16x4*)XP(t, c4 * 8);
      int m1 = t / 7, m2 = t % 7;
      int y  = wh * 7 + m1 + 3; if (y  >= 56) y  -= 56;
      int xx = ww * 7 + m2 + 3; if (xx >= 56) xx -= 56;
      float4 v = { (float)z[0], (float)z[1], (float)z[2], (float)z[3] };
      *(float4*)(outb + (size_t)(y * 56 + xx) * 192 + c4 * 4) = v;
    }
  }
#undef XP
}

extern "C" void kernel_launch(void* const* d_in, const int* in_sizes, int n_in,
                              void* d_out, int out_size, void* d_ws, size_t ws_size,
                              hipStream_t stream) {
  const float* x    = (const float*)d_in[0];
  const float* Wq   = (const float*)d_in[1];
  const float* bq   = (const float*)d_in[2];
  const float* Wo   = (const float*)d_in[3];
  const float* bo   = (const float*)d_in[4];
  const float* Brel = (const float*)d_in[5];

  f16*   wqd     = (f16*)d_ws;                         // 3*192*192*2 = 221184 B
  f16*   wod     = (f16*)((char*)d_ws + 0x38000);      // 192*192*2   =  73728 B
  float* bqd     = (float*)((char*)d_ws + 0x4A000);    // 3*192*4     =   2304 B
  f16*   biasreg = (f16*)((char*)d_ws + 0x4B000);      // 4*4*4*64*4*2=  32768 B

  hipLaunchKernelGGL(prep_kernel, dim3(256), dim3(256), 0, stream,
                     Wq, bq, Wo, Brel, wqd, wod, bqd, biasreg);
  hipLaunchKernelGGL(swin_kernel, dim3(32 * 8 * 8), dim3(384), 0, stream,
                     x, bqd, bo, wqd, wod, biasreg, (float*)d_out);
}

// Round 7
// 155.684 us; speedup vs baseline: 3.0515x; 1.3822x over previous
//
#include <hip/hip_runtime.h>

typedef _Float16 f16;
typedef _Float16 f16x4 __attribute__((ext_vector_type(4)));
typedef _Float16 f16x8 __attribute__((ext_vector_type(8)));
typedef float f32x4 __attribute__((ext_vector_type(4)));

#define MFMA32(A, B, C) __builtin_amdgcn_mfma_f32_16x16x32_f16((A), (B), (C), 0, 0, 0)
#if __has_builtin(__builtin_amdgcn_mfma_f32_16x16x16_f16)
#define MFMA16(A, B, C) __builtin_amdgcn_mfma_f32_16x16x16_f16((A), (B), (C), 0, 0, 0)
#else
#define MFMA16(A, B, C) __builtin_amdgcn_mfma_f32_16x16x16f16((A), (B), (C), 0, 0, 0)
#endif

// ---------------- prep: deinterleave weights to f16, bias tables ----------------
__global__ void prep_kernel(const float* __restrict__ Wq, const float* __restrict__ bqkv,
                            const float* __restrict__ Wo, const float* __restrict__ Brel,
                            f16* __restrict__ wqd, f16* __restrict__ wod,
                            float* __restrict__ bqd, f16* __restrict__ biasreg) {
  int tid = blockIdx.x * blockDim.x + threadIdx.x;
  int nthr = gridDim.x * blockDim.x;
  for (int i = tid; i < 3 * 192 * 192; i += nthr) {
    int c = i % 192, n = (i / 192) % 192, kk = i / (192 * 192);
    wqd[i] = (f16)Wq[(size_t)(n * 3 + kk) * 192 + c];
  }
  for (int i = tid; i < 192 * 192; i += nthr) wod[i] = (f16)Wo[i];
  for (int i = tid; i < 3 * 192; i += nthr) {
    int n = i % 192, kk = i / 192;
    bqd[i] = bqkv[n * 3 + kk];
  }
  for (int idx = tid; idx < 4 * 4 * 4 * 64 * 4; idx += nthr) {
    int m = idx & 3, lane = (idx >> 2) & 63, jt = (idx >> 8) & 3,
        itt = (idx >> 10) & 3, t = idx >> 12;
    int i = itt * 16 + (lane & 15);
    int j = jt * 16 + 4 * (lane >> 4) + m;
    float v = -60000.0f;
    if (i < 49 && j < 49) {
      bool msk = false;
      if (t & 2) msk |= ((i / 7 >= 4) != (j / 7 >= 4));
      if (t & 1) msk |= ((i % 7 >= 4) != (j % 7 >= 4));
      if (!msk) {
        // numpy PyArray_Arange + DOUBLE_fill: delta = fl(1+1/7) - 1
        volatile double one = 1.0;
        volatile double step = 1.0 / 7.0;
        volatile double b1 = one + step;
        volatile double delta = b1 - one;
        volatile double mj = (double)j * delta;
        volatile double sj = 1.0 + mj;
        volatile double mi = (double)i * delta;
        volatile double si = 1.0 + mi;
        double d = (double)sj - (double)si;
        int xd = (int)d;
        int yd = (j % 7) - (i % 7);
        int xm = ((xd % 13) + 13) % 13;
        int ym = ((yd % 13) + 13) % 13;
        v = Brel[xm * 13 + ym];
      }
    }
    biasreg[idx] = (f16)v;
  }
}

// ---------------- fused shifted-window MSA ----------------
// Block = 768 threads = 12 waves = 3 waves/SIMD (co-resident by construction):
// waves 0-5 = heads of window (b=2p), waves 6-11 = heads of window (b=2p+1),
// both at the same (wh,ww) so mask/bias fragments are shared.
// All intermediates in registers via K=16 MFMA C-chaining; 48 KB swizzled LDS
// (two 24 KB tiles) reused x -> O -> Z; epilogue writes full lines once.
__launch_bounds__(768, 3)
__global__ void swin_kernel(const float* __restrict__ x,
                            const float* __restrict__ bqd,
                            const float* __restrict__ bout,
                            const f16* __restrict__ wqd,
                            const f16* __restrict__ wod,
                            const f16* __restrict__ biasreg,
                            float* __restrict__ out) {
  __shared__ __align__(16) unsigned char xsm[2 * 64 * 384];  // per window: [row][192 f16], swizzled

  const int tid = threadIdx.x;
  const int bid = blockIdx.x;
  const int p  = bid >> 6;            // batch pair: b = 2p+t
  const int wh = (bid >> 3) & 7;
  const int ww = bid & 7;
  const int lane = tid & 63;
  const int wv = tid >> 6;            // 0..11
  const int t  = (wv >= 6) ? 1 : 0;   // window within pair
  const int hd = wv - 6 * t;          // head
  const int lr = lane & 15;
  const int lg = lane >> 4;

#define XP(tt, row, cb) ((void*)(xsm + (tt) * 24576 + (row) * 384 + ((cb) ^ (((row) & 7) << 4))))

  // ---- phase 0: stage both x windows (roll -4) into swizzled LDS, f16 ----
  {
    for (int idx = tid; idx < 2 * 49 * 48; idx += 768) {
      int tw = idx / (49 * 48), r = idx % (49 * 48);
      int tok = r / 48, c4 = r % 48;
      const float* xb = x + (size_t)(2 * p + tw) * (3136 * 192);
      int m1 = tok / 7, m2 = tok % 7;
      int y  = wh * 7 + m1 + 4; if (y  >= 56) y  -= 56;
      int xx = ww * 7 + m2 + 4; if (xx >= 56) xx -= 56;
      float4 v = *(const float4*)(xb + ((y * 56 + xx) * 192 + c4 * 4));
      f16x4 h = { (f16)v.x, (f16)v.y, (f16)v.z, (f16)v.w };
      *(f16x4*)XP(tw, tok, c4 * 8) = h;
    }
    for (int idx = tid; idx < 2 * 15 * 24; idx += 768) {   // zero rows 49..63
      int tw = idx / (15 * 24), r = idx % (15 * 24);
      int tok = 49 + r / 24, c8 = r % 24;
      f16x8 z = {};
      *(f16x8*)XP(tw, tok, c8 * 16) = z;
    }
  }
  __syncthreads();   // B1

  // ---- bias table (register layout; shared by both windows — same wh,ww) ----
  f16x4 br[4][4];
  {
    int msk = ((wh == 7) ? 2 : 0) | ((ww == 7) ? 1 : 0);
    #pragma unroll
    for (int itt = 0; itt < 4; ++itt)
      #pragma unroll
      for (int jt = 0; jt < 4; ++jt)
        br[itt][jt] = *(const f16x4*)(biasreg + ((((msk * 4 + itt) * 4 + jt) * 64 + lane) * 4));
  }

  // ---- phase 1a: Qt,Kt = W @ x^T  (C[n][i]: col i=lr, rows e=nt*16+4lg+m) ----
  f16x4 qtf[2][4], ktf[2][4];
  {
    f32x4 qacc[2][4], kacc[2][4];
    #pragma unroll
    for (int nt = 0; nt < 2; ++nt)
      #pragma unroll
      for (int it = 0; it < 4; ++it) {
        qacc[nt][it] = (f32x4){0.f, 0.f, 0.f, 0.f};
        kacc[nt][it] = (f32x4){0.f, 0.f, 0.f, 0.f};
      }
    #pragma unroll
    for (int ks = 0; ks < 6; ++ks) {
      f16x8 a[4];
      #pragma unroll
      for (int it = 0; it < 4; ++it)
        a[it] = *(const f16x8*)XP(t, it * 16 + lr, ks * 64 + lg * 16);
      #pragma unroll
      for (int nt = 0; nt < 2; ++nt) {
        const size_t roff = (size_t)(hd * 32 + nt * 16 + lr) * 192 + ks * 32 + lg * 8;
        f16x8 wqf = *(const f16x8*)(wqd + roff);                 // kk=0 plane
        f16x8 wkf = *(const f16x8*)(wqd + 192 * 192 + roff);     // kk=1 plane
        #pragma unroll
        for (int it = 0; it < 4; ++it) {
          qacc[nt][it] = MFMA32(wqf, a[it], qacc[nt][it]);
          kacc[nt][it] = MFMA32(wkf, a[it], kacc[nt][it]);
        }
      }
    }
    const float SCALE = 0.17677669529663687f;  // 1/sqrt(32) folded into Q
    #pragma unroll
    for (int nt = 0; nt < 2; ++nt) {
      float4 bq4 = *(const float4*)(bqd + hd * 32 + nt * 16 + 4 * lg);
      float4 bk4 = *(const float4*)(bqd + 192 + hd * 32 + nt * 16 + 4 * lg);
      #pragma unroll
      for (int it = 0; it < 4; ++it) {
        f16x4 q, k;
        q[0] = (f16)((qacc[nt][it][0] + bq4.x) * SCALE);
        q[1] = (f16)((qacc[nt][it][1] + bq4.y) * SCALE);
        q[2] = (f16)((qacc[nt][it][2] + bq4.z) * SCALE);
        q[3] = (f16)((qacc[nt][it][3] + bq4.w) * SCALE);
        k[0] = (f16)(kacc[nt][it][0] + bk4.x);
        k[1] = (f16)(kacc[nt][it][1] + bk4.y);
        k[2] = (f16)(kacc[nt][it][2] + bk4.z);
        k[3] = (f16)(kacc[nt][it][3] + bk4.w);
        qtf[nt][it] = q; ktf[nt][it] = k;
      }
    }
  }

  // ---- phase 2a: S^T = K @ Q^T ----
  f32x4 sacc[4][4];
  #pragma unroll
  for (int jt = 0; jt < 4; ++jt)
    #pragma unroll
    for (int it = 0; it < 4; ++it) {
      f32x4 c = (f32x4){0.f, 0.f, 0.f, 0.f};
      c = MFMA16(ktf[0][jt], qtf[0][it], c);
      sacc[jt][it] = MFMA16(ktf[1][jt], qtf[1][it], c);
    }

  // ---- softmax per query-col (rows j lane-local) ----
  f16x4 paf[4][4];   // [jt][it] normalized P as A-frags
  #pragma unroll
  for (int itt = 0; itt < 4; ++itt) {
    float sv[16];
    #pragma unroll
    for (int jt = 0; jt < 4; ++jt)
      #pragma unroll
      for (int m = 0; m < 4; ++m)
        sv[jt * 4 + m] = sacc[jt][itt][m] + (float)br[itt][jt][m];
    float mx = sv[0];
    #pragma unroll
    for (int q = 1; q < 16; ++q) mx = fmaxf(mx, sv[q]);
    mx = fmaxf(mx, __shfl_xor(mx, 16));
    mx = fmaxf(mx, __shfl_xor(mx, 32));
    float sum = 0.f;
    #pragma unroll
    for (int q = 0; q < 16; ++q) { sv[q] = __expf(sv[q] - mx); sum += sv[q]; }
    sum += __shfl_xor(sum, 16);
    sum += __shfl_xor(sum, 32);
    float rv = 1.0f / sum;
    #pragma unroll
    for (int jt = 0; jt < 4; ++jt) {
      f16x4 pk = { (f16)(sv[jt*4+0] * rv), (f16)(sv[jt*4+1] * rv),
                   (f16)(sv[jt*4+2] * rv), (f16)(sv[jt*4+3] * rv) };
      paf[jt][itt] = pk;
    }
  }

  // ---- phase 1b: V = x @ Wv^T  (C[j][e]) ----
  f16x4 vf[4][2];
  {
    f32x4 vacc[4][2];
    #pragma unroll
    for (int jt = 0; jt < 4; ++jt)
      #pragma unroll
      for (int et = 0; et < 2; ++et)
        vacc[jt][et] = (f32x4){0.f, 0.f, 0.f, 0.f};
    #pragma unroll
    for (int ks = 0; ks < 6; ++ks) {
      f16x8 a[4];
      #pragma unroll
      for (int jt = 0; jt < 4; ++jt)
        a[jt] = *(const f16x8*)XP(t, jt * 16 + lr, ks * 64 + lg * 16);
      #pragma unroll
      for (int et = 0; et < 2; ++et) {
        f16x8 wvf = *(const f16x8*)(wqd + 2 * 192 * 192 +
                      (size_t)(hd * 32 + et * 16 + lr) * 192 + ks * 32 + lg * 8);
        #pragma unroll
        for (int jt = 0; jt < 4; ++jt)
          vacc[jt][et] = MFMA32(a[jt], wvf, vacc[jt][et]);
      }
    }
    #pragma unroll
    for (int et = 0; et < 2; ++et) {
      float bv = bqd[2 * 192 + hd * 32 + et * 16 + lr];
      #pragma unroll
      for (int jt = 0; jt < 4; ++jt) {
        f16x4 v;
        #pragma unroll
        for (int m = 0; m < 4; ++m) v[m] = (f16)(vacc[jt][et][m] + bv);
        vf[jt][et] = v;
      }
    }
  }

  // ---- phase 2b: O = P @ V ----
  f32x4 oacc[4][2];
  #pragma unroll
  for (int it = 0; it < 4; ++it)
    #pragma unroll
    for (int et = 0; et < 2; ++et) {
      f32x4 c = (f32x4){0.f, 0.f, 0.f, 0.f};
      #pragma unroll
      for (int jt = 0; jt < 4; ++jt)
        c = MFMA16(paf[jt][it], vf[jt][et], c);
      oacc[it][et] = c;
    }

  __syncthreads();   // B2: all xs reads (phase 1a/1b) done everywhere

  // ---- O -> LDS (reuse xs region): O[i][head*32+e], swizzled ----
  #pragma unroll
  for (int it = 0; it < 4; ++it)
    #pragma unroll
    for (int et = 0; et < 2; ++et)
      #pragma unroll
      for (int m = 0; m < 4; ++m) {
        int i = it * 16 + 4 * lg + m;
        *(f16*)XP(t, i, hd * 64 + et * 32 + lr * 2) = (f16)(oacc[it][et][m]);
      }
  __syncthreads();   // B3

  // ---- phase 3: Z = O @ Wo^T + bo ----
  f32x4 zacc[2][4];
  {
    #pragma unroll
    for (int nt = 0; nt < 2; ++nt)
      #pragma unroll
      for (int it = 0; it < 4; ++it)
        zacc[nt][it] = (f32x4){0.f, 0.f, 0.f, 0.f};
    #pragma unroll
    for (int ks = 0; ks < 6; ++ks) {
      f16x8 a[4];
      #pragma unroll
      for (int it = 0; it < 4; ++it)
        a[it] = *(const f16x8*)XP(t, it * 16 + lr, ks * 64 + lg * 16);
      #pragma unroll
      for (int nt = 0; nt < 2; ++nt) {
        f16x8 bw = *(const f16x8*)(wod + (size_t)(hd * 32 + nt * 16 + lr) * 192 + ks * 32 + lg * 8);
        #pragma unroll
        for (int it = 0; it < 4; ++it)
          zacc[nt][it] = MFMA32(a[it], bw, zacc[nt][it]);
      }
    }
  }
  __syncthreads();   // B4: all xs reads (phase 3) done -> reuse xs for Z

  // ---- Z (+bias, f16) -> LDS ----
  #pragma unroll
  for (int nt = 0; nt < 2; ++nt) {
    int n = hd * 32 + nt * 16 + lr;
    float bo = bout[n];
    #pragma unroll
    for (int it = 0; it < 4; ++it)
      #pragma unroll
      for (int m = 0; m < 4; ++m) {
        int i = it * 16 + 4 * lg + m;
        *(f16*)XP(t, i, n * 2) = (f16)(zacc[nt][it][m] + bo);
      }
  }
  __syncthreads();   // B5

  // ---- cooperative fully-coalesced out write (full 128B lines, once) ----
  {
    for (int idx = tid; idx < 2 * 49 * 48; idx += 768) {
      int tw = idx / (49 * 48), r = idx % (49 * 48);
      int tok = r / 48, c4 = r % 48;
      float* outb = out + (size_t)(2 * p + tw) * (3136 * 192);
      f16x4 z = *(const f16x4*)XP(tw, tok, c4 * 8);
      int m1 = tok / 7, m2 = tok % 7;
      int y  = wh * 7 + m1 + 3; if (y  >= 56) y  -= 56;
      int xx = ww * 7 + m2 + 3; if (xx >= 56) xx -= 56;
      float4 v = { (float)z[0], (float)z[1], (float)z[2], (float)z[3] };
      *(float4*)(outb + (size_t)(y * 56 + xx) * 192 + c4 * 4) = v;
    }
  }
#undef XP
}

extern "C" void kernel_launch(void* const* d_in, const int* in_sizes, int n_in,
                              void* d_out, int out_size, void* d_ws, size_t ws_size,
                              hipStream_t stream) {
  const float* x    = (const float*)d_in[0];
  const float* Wq   = (const float*)d_in[1];
  const float* bq   = (const float*)d_in[2];
  const float* Wo   = (const float*)d_in[3];
  const float* bo   = (const float*)d_in[4];
  const float* Brel = (const float*)d_in[5];

  f16*   wqd     = (f16*)d_ws;                         // 3*192*192*2 = 221184 B
  f16*   wod     = (f16*)((char*)d_ws + 0x38000);      // 192*192*2   =  73728 B
  float* bqd     = (float*)((char*)d_ws + 0x4A000);    // 3*192*4     =   2304 B
  f16*   biasreg = (f16*)((char*)d_ws + 0x4B000);      // 4*4*4*64*4*2=  32768 B

  hipLaunchKernelGGL(prep_kernel, dim3(256), dim3(256), 0, stream,
                     Wq, bq, Wo, Brel, wqd, wod, bqd, biasreg);
  hipLaunchKernelGGL(swin_kernel, dim3(16 * 8 * 8), dim3(768), 0, stream,
                     x, bqd, bo, wqd, wod, biasreg, (float*)d_out);
}